// Round 2
// baseline (22.077 us; speedup 1.0000x reference)
//
#include <hip/hip_runtime.h>
#include <math.h>

#define SIGMA 0.2f
#define LOG2E 1.4426950408889634f

// One wave (64 lanes) per output row i: lane = kernel index m (0..63).
// 16 waves (1024 threads) per block -> 3125 blocks for n=50000, one row per
// wave, no grid-stride loop: maximize TLP to hide the dependent
// neighbour->gather latency chain.
// Kernel points computed once per block into LDS with hardware trig
// (__sinf/__cosf), stored transposed [l][m] (conflict-free reads) and
// pre-scaled by log2e/sigma^2.
__global__ __launch_bounds__(1024) void corr_kernel(
    const float* __restrict__ normal,
    const int*   __restrict__ neighbour,
    const float* __restrict__ theta,
    const float* __restrict__ phi,
    float*       __restrict__ out,
    int n)
{
    __shared__ float kx[256], ky[256], kz[256];   // [l][m] layout, pre-scaled
    const int t = threadIdx.x;

    if (t < 256) {
        const int km = t >> 2;      // kernel index m
        const int kl = t & 3;       // kernel point l
        float th = theta[t];
        float ph = phi[t];
        float st = __sinf(th), ct = __cosf(th);
        float sp = __sinf(ph), cp = __cosf(ph);
        const float s = LOG2E / (SIGMA * SIGMA);
        kx[kl * 64 + km] = st * sp * s;   // sin(theta)*sin(phi) * s
        ky[kl * 64 + km] = st * cp * s;   // sin(theta)*cos(phi) * s
        kz[kl * 64 + km] = ct * s;        // cos(theta) * s
    }
    __syncthreads();

    const int m = t & 63;           // lane = kernel index
    const int w = t >> 6;           // wave id within block
    const int i = blockIdx.x * 16 + w;
    if (i >= n) return;

    // Issue all global loads up front (wave-uniform -> broadcast).
    const int id1 = neighbour[i * 3 + 0];
    const int id2 = neighbour[i * 3 + 1];
    const int id3 = neighbour[i * 3 + 2];

    float px[4], py[4], pz[4];
    px[0] = normal[(long long)i * 3 + 0];
    py[0] = normal[(long long)i * 3 + 1];
    pz[0] = normal[(long long)i * 3 + 2];
    px[1] = normal[(long long)id1 * 3 + 0];
    py[1] = normal[(long long)id1 * 3 + 1];
    pz[1] = normal[(long long)id1 * 3 + 2];
    px[2] = normal[(long long)id2 * 3 + 0];
    py[2] = normal[(long long)id2 * 3 + 1];
    pz[2] = normal[(long long)id2 * 3 + 2];
    px[3] = normal[(long long)id3 * 3 + 0];
    py[3] = normal[(long long)id3 * 3 + 1];
    pz[3] = normal[(long long)id3 * 3 + 2];

    // Per-lane kernel points (pre-scaled), conflict-free LDS reads.
    float kxs[4], kys[4], kzs[4];
#pragma unroll
    for (int l = 0; l < 4; ++l) {
        kxs[l] = kx[l * 64 + m];
        kys[l] = ky[l * 64 + m];
        kzs[l] = kz[l * 64 + m];
    }

    const float c1 = -LOG2E / (2.0f * SIGMA * SIGMA); // multiplies (|p|^2 + 1)

    float acc0 = 0.0f, acc1 = 0.0f;
#pragma unroll
    for (int p = 0; p < 4; ++p) {
        const float c2 = (px[p] * px[p] + py[p] * py[p] + pz[p] * pz[p] + 1.0f) * c1;
        acc0 += __builtin_amdgcn_exp2f(fmaf(px[p], kxs[0], fmaf(py[p], kys[0], fmaf(pz[p], kzs[0], c2))));
        acc1 += __builtin_amdgcn_exp2f(fmaf(px[p], kxs[1], fmaf(py[p], kys[1], fmaf(pz[p], kzs[1], c2))));
        acc0 += __builtin_amdgcn_exp2f(fmaf(px[p], kxs[2], fmaf(py[p], kys[2], fmaf(pz[p], kzs[2], c2))));
        acc1 += __builtin_amdgcn_exp2f(fmaf(px[p], kxs[3], fmaf(py[p], kys[3], fmaf(pz[p], kzs[3], c2))));
    }

    out[(long long)i * 64 + m] = (acc0 + acc1) * (1.0f / 16.0f);
}

extern "C" void kernel_launch(void* const* d_in, const int* in_sizes, int n_in,
                              void* d_out, int out_size, void* d_ws, size_t ws_size,
                              hipStream_t stream) {
    const float* normal    = (const float*)d_in[0];
    const int*   neighbour = (const int*)d_in[1];
    const float* theta     = (const float*)d_in[2];
    const float* phi       = (const float*)d_in[3];
    float*       out       = (float*)d_out;

    const int n = in_sizes[0] / 3;   // 50000
    const int blocks = (n + 15) / 16;

    hipLaunchKernelGGL(corr_kernel, dim3(blocks), dim3(1024), 0, stream,
                       normal, neighbour, theta, phi, out, n);
}